// Round 4
// baseline (5707.981 us; speedup 1.0000x reference)
//
#include <hip/hip_runtime.h>

typedef unsigned short u16;
typedef __attribute__((ext_vector_type(8))) short s16x8;
typedef __attribute__((ext_vector_type(4))) short s16x4;
typedef __attribute__((ext_vector_type(4))) float f32x4;

#define MFMA16(a, b, c) __builtin_amdgcn_mfma_f32_16x16x32_bf16(a, b, c, 0, 0, 0)

__device__ __forceinline__ u16 f2bf(float f) {
  unsigned u = __float_as_uint(f);
  u += 0x7FFFu + ((u >> 16) & 1u);
  return (u16)(u >> 16);
}

// async 16B global->LDS. LDS dest is wave-uniform base + lane*16.
__device__ __forceinline__ void async_cp16(const u16* g, u16* l) {
  __builtin_amdgcn_global_load_lds(
      (__attribute__((address_space(1))) void*)g,
      (__attribute__((address_space(3))) void*)l,
      16, 0, 0);
}

// ---------------- conversion kernels ----------------
__global__ void cvt4(const float* __restrict__ s, u16* __restrict__ d, int n4) {
  int i = blockIdx.x * 256 + threadIdx.x;
  if (i >= n4) return;
  f32x4 v = *(const f32x4*)(s + 4L * i);
  s16x4 o;
  o[0] = (short)f2bf(v[0]); o[1] = (short)f2bf(v[1]);
  o[2] = (short)f2bf(v[2]); o[3] = (short)f2bf(v[3]);
  *(s16x4*)(d + 4L * i) = o;
}

// final_weight [256][256] fp32 -> transposed bf16
__global__ void cvt_t(const float* __restrict__ s, u16* __restrict__ d) {
  int j = blockIdx.x, k = threadIdx.x;
  d[j * 256 + k] = f2bf(s[k * 256 + j]);
}

// ---------------- fused QKV projection GEMM ----------------
// grid (64, gc, 3). z=0: Q=(x@Wq^T+bq)*(log2e/16) row-major. z=1: K row-major.
// z=2: V^T=Wv@x^T (+bv per dim row), written PRE-TILED in attn's LDS layout.
__global__ __launch_bounds__(256, 4) void gemm_qkv(
    const u16* __restrict__ xb, const u16* __restrict__ wq, const u16* __restrict__ wk,
    const u16* __restrict__ wv, const float* __restrict__ bqv,
    const float* __restrict__ bkv, const float* __restrict__ bvv,
    u16* __restrict__ qkv, int c0) {
  __shared__ __align__(16) u16 lds[16384];
  const int z = blockIdx.z, g = blockIdx.y;
  const u16* A; const u16* B; const float* bias; u16* out;
  int tiles_n;
  if (z == 0)      { A = xb; B = wq + (long)(c0 + g) * 65536; bias = bqv + (long)(c0 + g) * 256;
                     out = qkv + (long)g * 3145728;           tiles_n = 2; }
  else if (z == 1) { A = xb; B = wk + (long)(c0 + g) * 65536; bias = bkv + (long)(c0 + g) * 256;
                     out = qkv + (long)g * 3145728 + 1048576; tiles_n = 2; }
  else             { A = wv + (long)(c0 + g) * 65536; B = xb; bias = bvv + (long)(c0 + g) * 256;
                     out = qkv + (long)g * 3145728 + 2097152; tiles_n = 32; }

  const int tid = threadIdx.x;
  const int lane = tid & 63;
  const int l15 = lane & 15, q4 = lane >> 4;
  const int w = tid >> 6;
  const int qm = w >> 1, qn = w & 1;
  const int tm = blockIdx.x / tiles_n, tn = blockIdx.x % tiles_n;
  const int row0 = tm << 7, col0 = tn << 7;

  f32x4 C[4][4];
#pragma unroll
  for (int i = 0; i < 4; ++i)
#pragma unroll
    for (int j = 0; j < 4; ++j) C[i][j] = (f32x4)0.0f;

  u16* Al = lds;
  u16* Bl = lds + 8192;

  for (int kc = 0; kc < 4; ++kc) {
    __syncthreads();
#pragma unroll
    for (int i = 0; i < 4; ++i) {
      int s = tid + i * 256;
      int r = s >> 3, p = s & 7;
      async_cp16(A + (long)(row0 + r) * 256 + kc * 64 + ((p ^ (r & 7)) << 3), Al + s * 8);
    }
#pragma unroll
    for (int i = 0; i < 4; ++i) {
      int s = tid + i * 256;
      int r = s >> 3, p = s & 7;
      async_cp16(B + (long)(col0 + r) * 256 + kc * 64 + ((p ^ (r & 7)) << 3), Bl + s * 8);
    }
    __syncthreads();
#pragma unroll
    for (int ks = 0; ks < 2; ++ks) {
      s16x8 a[4];
#pragma unroll
      for (int mt = 0; mt < 4; ++mt) {
        int r = qm * 64 + mt * 16 + l15;
        int kb = ks * 4 + q4;
        a[mt] = *(const s16x8*)(Al + r * 64 + ((kb ^ (r & 7)) << 3));
      }
#pragma unroll
      for (int nt = 0; nt < 4; ++nt) {
        int rn = qn * 64 + nt * 16 + l15;
        int kb = ks * 4 + q4;
        s16x8 b = *(const s16x8*)(Bl + rn * 64 + ((kb ^ (rn & 7)) << 3));
#pragma unroll
        for (int mt = 0; mt < 4; ++mt) C[mt][nt] = MFMA16(a[mt], b, C[mt][nt]);
      }
    }
  }

  const int gr0 = row0 + qm * 64, gc0 = col0 + qn * 64;
  if (z < 2) {
    const float sc = (z == 0) ? 0.0625f * 1.44269504f : 1.0f;
#pragma unroll
    for (int nt = 0; nt < 4; ++nt) {
      int cc = gc0 + nt * 16 + l15;
      float bc = bias[cc];
#pragma unroll
      for (int mt = 0; mt < 4; ++mt)
#pragma unroll
        for (int e = 0; e < 4; ++e) {
          int rr = gr0 + mt * 16 + q4 * 4 + e;
          out[(long)rr * 256 + cc] = f2bf((C[mt][nt][e] + bc) * sc);
        }
    }
  } else {
    float bm[4][4];
#pragma unroll
    for (int mt = 0; mt < 4; ++mt)
#pragma unroll
      for (int e = 0; e < 4; ++e) bm[mt][e] = bias[gr0 + mt * 16 + q4 * 4 + e];
#pragma unroll
    for (int nt = 0; nt < 4; ++nt) {
      int cc = gc0 + nt * 16 + l15;
#pragma unroll
      for (int mt = 0; mt < 4; ++mt)
#pragma unroll
        for (int e = 0; e < 4; ++e) {
          int rr = gr0 + mt * 16 + q4 * 4 + e;  // dim
          long ad = (long)(cc >> 5) * 8192 + ((cc >> 3) & 3) * 2048 + rr * 8 + (cc & 7);
          out[ad] = f2bf(C[mt][nt][e] + bm[mt][e]);
        }
    }
  }
}

// ---------------- MLP / final GEMM ----------------
template <int MODE>
__global__ __launch_bounds__(256, 4) void gemm_bt(
    const u16* __restrict__ A, const u16* __restrict__ B, void* __restrict__ Cout,
    const float* __restrict__ bias) {
  __shared__ __align__(16) u16 lds[16384];
  const int tid = threadIdx.x;
  const int lane = tid & 63;
  const int l15 = lane & 15, q4 = lane >> 4;
  const int w = tid >> 6;
  const int qm = w >> 1, qn = w & 1;
  const int tm = blockIdx.x >> 1, tn = blockIdx.x & 1;
  const int row0 = tm << 7, col0 = tn << 7;

  f32x4 C[4][4];
#pragma unroll
  for (int i = 0; i < 4; ++i)
#pragma unroll
    for (int j = 0; j < 4; ++j) C[i][j] = (f32x4)0.0f;

  u16* Al = lds;
  u16* Bl = lds + 8192;

  for (int kc = 0; kc < 4; ++kc) {
    __syncthreads();
#pragma unroll
    for (int i = 0; i < 4; ++i) {
      int s = tid + i * 256;
      int r = s >> 3, p = s & 7;
      async_cp16(A + (long)(row0 + r) * 256 + kc * 64 + ((p ^ (r & 7)) << 3), Al + s * 8);
    }
#pragma unroll
    for (int i = 0; i < 4; ++i) {
      int s = tid + i * 256;
      int r = s >> 3, p = s & 7;
      async_cp16(B + (long)(col0 + r) * 256 + kc * 64 + ((p ^ (r & 7)) << 3), Bl + s * 8);
    }
    __syncthreads();
#pragma unroll
    for (int ks = 0; ks < 2; ++ks) {
      s16x8 a[4];
#pragma unroll
      for (int mt = 0; mt < 4; ++mt) {
        int r = qm * 64 + mt * 16 + l15;
        int kb = ks * 4 + q4;
        a[mt] = *(const s16x8*)(Al + r * 64 + ((kb ^ (r & 7)) << 3));
      }
#pragma unroll
      for (int nt = 0; nt < 4; ++nt) {
        int rn = qn * 64 + nt * 16 + l15;
        int kb = ks * 4 + q4;
        s16x8 b = *(const s16x8*)(Bl + rn * 64 + ((kb ^ (rn & 7)) << 3));
#pragma unroll
        for (int mt = 0; mt < 4; ++mt) C[mt][nt] = MFMA16(a[mt], b, C[mt][nt]);
      }
    }
  }

  const int gr0 = row0 + qm * 64, gc0 = col0 + qn * 64;
#pragma unroll
  for (int nt = 0; nt < 4; ++nt) {
    int cc = gc0 + nt * 16 + l15;
    float bc = bias[cc];
#pragma unroll
    for (int mt = 0; mt < 4; ++mt)
#pragma unroll
      for (int e = 0; e < 4; ++e) {
        int rr = gr0 + mt * 16 + q4 * 4 + e;
        float v = C[mt][nt][e];
        if (MODE == 2) {
          v = fmaxf(v + bc, 0.0f);
          ((u16*)Cout)[(long)rr * 256 + cc] = f2bf(v);
        } else {
          v = 1.0f / (1.0f + __expf(-v)) + bc;
          ((float*)Cout)[(long)rr * 256 + cc] = v;
        }
      }
  }
}

// ---------------- fused flash attention (software-pipelined) ----------------
// Per iter jt: B1 | PV_A(jt-1) | S(jt) | PV_B(jt-1) | B2 | DMA(jt+1) | softmax(jt)
// Softmax chain and P LDS-latency are covered by next iter's PV_A/S.
// Row sums in VALU (fp32 partials per lane, shfl-reduced at end).
__global__ __launch_bounds__(256, 2) void attn(const u16* __restrict__ qkv,
                                               float* __restrict__ acc, int gc, int swiz) {
  __shared__ __align__(16) u16 lds[37888];  // K0|K1|V0|V1|P(128x40)
  u16* const Pl = lds + 32768;

  const int f = blockIdx.x;
  int b, tile;
  if (swiz) { b = (f & 7) + ((f >> 8) << 3); tile = (f >> 3) & 31; }
  else { b = f >> 5; tile = f & 31; }
  if (b >= gc) return;

  const int tid = threadIdx.x;
  const int lane = tid & 63, w = tid >> 6;
  const int l15 = lane & 15, q4 = lane >> 4;
  const long slot = 3145728L * b;
  const u16* Qg = qkv + slot;
  const u16* Kg = qkv + slot + 1048576;
  const u16* Vg = qkv + slot + 2097152;
  const int rw = tile * 128 + w * 32;

  const int krow = tid >> 3;
  const int ksw = (tid & 7) ^ (krow & 7);
  const int kb0 = l15 * 64 + ((q4 ^ (l15 & 7)) << 3);
  const int kb1 = kb0 ^ 32;
  const int vrb = (l15 + (q4 << 8)) << 3;
  const int pwb = (w * 32 + q4 * 4) * 40 + l15;
  const int pra = (w * 32 + l15) * 40 + q4 * 8;

  // Q fragments (pre-scaled by log2e/16): 2 m-tiles x 8 k-slabs
  s16x8 qf[2][8];
#pragma unroll
  for (int mt = 0; mt < 2; ++mt) {
    const u16* qr = Qg + (long)(rw + mt * 16 + l15) * 256 + q4 * 8;
#pragma unroll
    for (int ks = 0; ks < 8; ++ks) qf[mt][ks] = *(const s16x8*)(qr + ks * 32);
  }

  f32x4 O[2][16];
#pragma unroll
  for (int mt = 0; mt < 2; ++mt)
#pragma unroll
    for (int nt = 0; nt < 16; ++nt) O[mt][nt] = (f32x4)0.0f;
  float rs[2][4];
#pragma unroll
  for (int mt = 0; mt < 2; ++mt)
#pragma unroll
    for (int e = 0; e < 4; ++e) rs[mt][e] = 0.0f;

  s16x8 a0p, a1p;  // P A-frags of previous iter (set at each iter's end)

  // stage tile 0 into parity-0 buffers
#pragma unroll
  for (int i = 0; i < 4; ++i)
    async_cp16(Kg + krow * 256 + ((i * 8 + ksw) << 3), lds + (tid + i * 256) * 8);
#pragma unroll
  for (int i = 0; i < 4; ++i)
    async_cp16(Vg + (tid + i * 256) * 8, lds + 16384 + (tid + i * 256) * 8);

  for (int jt = 0; jt < 128; ++jt) {
    const int cb = (jt & 1) << 13;  // u16 offset: 8192 per buffer
    const u16* Kc = lds + cb;
    const u16* Vc = lds + 16384 + cb;
    const u16* Vp = lds + 16384 + (cb ^ 8192);  // V(jt-1)
    __syncthreads();  // B1: K(jt),V(jt) DMA drained (issued one iter ago)

    // PV_A(jt-1): n-tiles 0..7
    if (jt > 0) {
#pragma unroll
      for (int nt = 0; nt < 8; ++nt) {
        s16x8 bfr = *(const s16x8*)(Vp + vrb + nt * 128);
        O[0][nt] = MFMA16(a0p, bfr, O[0][nt]);
        O[1][nt] = MFMA16(a1p, bfr, O[1][nt]);
      }
    }

    // S(jt) = Q K^T (pre-scaled by log2e/16)
    f32x4 S[2][2];
    S[0][0] = (f32x4)0.0f; S[0][1] = (f32x4)0.0f;
    S[1][0] = (f32x4)0.0f; S[1][1] = (f32x4)0.0f;
#pragma unroll
    for (int ks = 0; ks < 8; ++ks) {
      const u16* kp = Kc + ((ks & 1) ? kb1 : kb0) + (ks >> 1) * 2048;
#pragma unroll
      for (int nt = 0; nt < 2; ++nt) {
        s16x8 bfr = *(const s16x8*)(kp + nt * 1024);
        S[0][nt] = MFMA16(qf[0][ks], bfr, S[0][nt]);
        S[1][nt] = MFMA16(qf[1][ks], bfr, S[1][nt]);
      }
    }

    // PV_B(jt-1): n-tiles 8..15 (fills the S MFMA tail)
    if (jt > 0) {
#pragma unroll
      for (int nt = 8; nt < 16; ++nt) {
        s16x8 bfr = *(const s16x8*)(Vp + vrb + nt * 128);
        O[0][nt] = MFMA16(a0p, bfr, O[0][nt]);
        O[1][nt] = MFMA16(a1p, bfr, O[1][nt]);
      }
    }

    __syncthreads();  // B2: all waves done reading V(jt-1) / K(jt); no DMA in flight

    if (jt < 127) {  // DMA tile jt+1 into parity (jt+1) buffers; drained at next B1
      const u16* Kn = Kg + (jt + 1) * 8192;
      const u16* Vn = Vg + (jt + 1) * 8192;
      u16* Kd = lds + (cb ^ 16384);
      u16* Vd = lds + 16384 + (cb ^ 16384);
#pragma unroll
      for (int i = 0; i < 4; ++i)
        async_cp16(Kn + krow * 256 + ((i * 8 + ksw) << 3), Kd + (tid + i * 256) * 8);
#pragma unroll
      for (int i = 0; i < 4; ++i)
        async_cp16(Vn + (tid + i * 256) * 8, Vd + (tid + i * 256) * 8);
    }

    // softmax(jt): p = exp2(sigmoid_via_exp2(s)*log2e); fp32 row-sum partials
#pragma unroll
    for (int mt = 0; mt < 2; ++mt)
#pragma unroll
      for (int e = 0; e < 4; ++e) {
        float p0, p1;
#pragma unroll
        for (int nt = 0; nt < 2; ++nt) {
          float sv = S[mt][nt][e];
          float t = exp2f(-sv);
          float sig = __builtin_amdgcn_rcpf(1.0f + t);
          float p = exp2f(sig * 1.44269504f);
          if (nt == 0) p0 = p; else p1 = p;
          unsigned u = __float_as_uint(p) + 0x8000u;  // round-half-up to bf16
          Pl[pwb + mt * 640 + e * 40 + nt * 16] = (u16)(u >> 16);
        }
        rs[mt][e] += p0 + p1;
      }

    // A-frags for next iter's PV (own rows; lgkmcnt-tracked, no barrier)
    a0p = *(const s16x8*)(Pl + pra);
    a1p = *(const s16x8*)(Pl + pra + 640);
  }

  // final PV(127): V parity 1
  {
    const u16* Vp = lds + 16384 + 8192;
#pragma unroll
    for (int nt = 0; nt < 16; ++nt) {
      s16x8 bfr = *(const s16x8*)(Vp + vrb + nt * 128);
      O[0][nt] = MFMA16(a0p, bfr, O[0][nt]);
      O[1][nt] = MFMA16(a1p, bfr, O[1][nt]);
    }
  }

  // reduce row sums across the 16 lanes of each quad-row group, then normalize
#pragma unroll
  for (int mt = 0; mt < 2; ++mt) {
    float rls[4];
#pragma unroll
    for (int e = 0; e < 4; ++e) {
      float v = rs[mt][e];
      v += __shfl_xor(v, 1, 64);
      v += __shfl_xor(v, 2, 64);
      v += __shfl_xor(v, 4, 64);
      v += __shfl_xor(v, 8, 64);
      rls[e] = 0.005f * __builtin_amdgcn_rcpf(v);
    }
#pragma unroll
    for (int nt = 0; nt < 16; ++nt) {
#pragma unroll
      for (int e = 0; e < 4; ++e) {
        int rr = rw + mt * 16 + q4 * 4 + e;
        int cc = nt * 16 + l15;
        unsafeAtomicAdd(acc + (long)rr * 256 + cc, O[mt][nt][e] * rls[e]);
      }
    }
  }
}

// ---------------- host ----------------
extern "C" void kernel_launch(void* const* d_in, const int* in_sizes, int n_in,
                              void* d_out, int out_size, void* d_ws, size_t ws_size,
                              hipStream_t stream) {
  const float* x = (const float*)d_in[0];
  const float* Wq = (const float*)d_in[1];
  const float* bq = (const float*)d_in[2];
  const float* Wk = (const float*)d_in[3];
  const float* bk = (const float*)d_in[4];
  const float* Wv = (const float*)d_in[5];
  const float* bv = (const float*)d_in[6];
  const float* Wl = (const float*)d_in[7];
  const float* bl = (const float*)d_in[8];
  const float* fw = (const float*)d_in[9];
  const float* fb = (const float*)d_in[10];
  float* out = (float*)d_out;

  u16* wsb = (u16*)d_ws;
  u16* xb = wsb;                    // 1,048,576
  u16* wqb = wsb + 1048576;         // 13,107,200
  u16* wkb = wqb + 13107200;
  u16* wvb = wkb + 13107200;
  u16* wlb = wvb + 13107200;        // 1,310,720
  u16* fwtb = wlb + 1310720;        // 65,536
  u16* h0 = fwtb + 65536;           // 1,048,576
  u16* h1 = h0 + 1048576;
  u16* qkvb = h1 + 1048576;         // G * 3,145,728 elems

  long fixedBytes = (long)((char*)qkvb - (char*)wsb);
  long avail = (long)ws_size - fixedBytes;
  int G = (int)(avail / 6291456L);
  if (G > 16) G = 16;  // 16 blocks x 32 tiles = 512 WGs = exactly 2/CU
  if (G < 1) G = 1;

  hipMemsetAsync(d_out, 0, (size_t)out_size * sizeof(float), stream);

  cvt4<<<dim3(1024), 256, 0, stream>>>(x, xb, 262144);
  cvt4<<<dim3(12800), 256, 0, stream>>>(Wq, wqb, 3276800);
  cvt4<<<dim3(12800), 256, 0, stream>>>(Wk, wkb, 3276800);
  cvt4<<<dim3(12800), 256, 0, stream>>>(Wv, wvb, 3276800);
  cvt4<<<dim3(1280), 256, 0, stream>>>(Wl, wlb, 327680);
  cvt_t<<<dim3(256), 256, 0, stream>>>(fw, fwtb);

  for (int c0 = 0; c0 < 200; c0 += G) {
    int gc = (200 - c0 < G) ? (200 - c0) : G;
    gemm_qkv<<<dim3(64, gc, 3), 256, 0, stream>>>(xb, wqb, wkb, wvb, bq, bk, bv, qkvb, c0);
    int swiz = (gc == 16 || gc == 8) ? 1 : 0;
    attn<<<dim3(32 * gc), 256, 0, stream>>>(qkvb, out, gc, swiz);
  }

  // MLP: h0 = bf16(acc); 20 x relu-GEMM ping-pong; final sigmoid head
  cvt4<<<dim3(1024), 256, 0, stream>>>(out, h0, 262144);
  for (int i = 0; i < 20; ++i) {
    u16* hin = (i & 1) ? h1 : h0;
    u16* hout = (i & 1) ? h0 : h1;
    gemm_bt<2><<<dim3(64), 256, 0, stream>>>(hin, wlb + (long)i * 65536, hout,
                                             bl + (long)i * 256);
  }
  gemm_bt<3><<<dim3(64), 256, 0, stream>>>(h0, fwtb, d_out, fb);
}